// Round 4
// baseline (2442.047 us; speedup 1.0000x reference)
//
#include <hip/hip_runtime.h>

#define DTC 0.01f
#define LAM  2.88539008178f     // 2/ln2
#define L2E  1.44269504089f     // 1/ln2

typedef __attribute__((ext_vector_type(8))) short short8;
typedef __attribute__((ext_vector_type(4))) float floatx4;

#if __has_builtin(__builtin_amdgcn_exp2f)
#define EXP2F(x) __builtin_amdgcn_exp2f(x)
#else
#define EXP2F(x) exp2f(x)
#endif
#if __has_builtin(__builtin_amdgcn_rcpf)
#define RCPF(x) __builtin_amdgcn_rcpf(x)
#else
#define RCPF(x) (1.0f / (x))
#endif

__device__ __forceinline__ unsigned short f2bf(float f) {
    unsigned u = __float_as_uint(f);
    u += 0x7FFFu + ((u >> 16) & 1u);
    return (unsigned short)(u >> 16);
}
// 1/(1+2^y): gate pre-acts pre-scaled by -1/ln2 -> sigmoid; by +2/ln2 -> tanh = 1-2*rcp1p.
__device__ __forceinline__ float rcp1p(float y) {
    return RCPF(1.0f + EXP2F(y));
}
// Drains LDS ops (cross-wave visibility) but NOT vmcnt: out/res stores fly across barriers.
__device__ __forceinline__ void wg_barrier() {
    asm volatile("s_waitcnt lgkmcnt(0)" ::: "memory");
    __builtin_amdgcn_s_barrier();
}
// r[l<32] = lo[l]; r[l>=32] = hi[l-32]
__device__ __forceinline__ float lane_merge(float lo, float hi) {
#if __has_builtin(__builtin_amdgcn_permlane32_swap)
    typedef __attribute__((ext_vector_type(2))) unsigned int uint2v;
    uint2v r = __builtin_amdgcn_permlane32_swap(__float_as_uint(lo), __float_as_uint(hi),
                                                false, false);
    return __uint_as_float(r[0]);
#else
    unsigned a = __float_as_uint(lo), b = __float_as_uint(hi);
    asm volatile("v_permlane32_swap_b32 %0, %1" : "+v"(a), "+v"(b));
    return __uint_as_float(a);
#endif
}

#define U1S 136   // bf16 stride; 272B = 16*17 spreads b128 reads over banks

#define MFMA(a, b, c) __builtin_amdgcn_mfma_f32_16x16x32_bf16((a), (b), (c), 0, 0, 0)

// gs-update + q0 (gates0 pre-act) + p1 (layer-1 h_b partial) for one group.
__device__ __forceinline__ void mfma_phase1(
    const short8& a0, const short8& a1, const short8& a2, const short8& a3,
    const short8 B0[4][2], const short8 B1[4][4], const short8 M2f[4][2],
    floatx4 gs[4], const float gd[4], const float b1s[4],
    floatx4 q0[4], floatx4 p1[4])
{
    #pragma unroll
    for (int j = 0; j < 4; ++j) {
        floatx4 z = gs[j];                 // gs(t) = gs(t-1) + M2f*h_b(t-1) + gd
        z = MFMA(a2, M2f[j][0], z);
        z = MFMA(a3, M2f[j][1], z);
        #pragma unroll
        for (int r = 0; r < 4; ++r) z[r] += gd[j];
        gs[j] = z;
        floatx4 q = z;                     // q0 = gs(t) + B0*h_a(t-1)
        q = MFMA(a0, B0[j][0], q);
        q = MFMA(a1, B0[j][1], q);
        q0[j] = q;
        floatx4 pz = {b1s[j], b1s[j], b1s[j], b1s[j]};
        pz = MFMA(a2, B1[j][2], pz);       // layer-1 partial over h_b(t-1)
        pz = MFMA(a3, B1[j][3], pz);
        p1[j] = pz;
    }
}

// Compact 8 real C-rows onto 64 lanes, run the cell nonlinearity, write h (bf16).
__device__ __forceinline__ void cell_trans(const floatx4 q[4], float cst[2],
                                           unsigned short* Hw)
{
    float P[2][4];
    #pragma unroll
    for (int j = 0; j < 4; ++j) {
        P[0][j] = lane_merge(q[j][0], q[j][2]);
        P[1][j] = lane_merge(q[j][1], q[j][3]);
    }
    #pragma unroll
    for (int e = 0; e < 2; ++e) {
        float iv = rcp1p(P[e][0]);
        float fv = rcp1p(P[e][1]);
        float gr = rcp1p(P[e][2]);
        float ov = rcp1p(P[e][3]);
        float gl = __builtin_fmaf(gr, -2.0f * LAM, LAM);   // LAM*tanh(g)
        float c  = __builtin_fmaf(fv, cst[e], iv * gl);    // LAM-scaled cell
        cst[e]   = c;
        float r2 = rcp1p(c);
        float h  = __builtin_fmaf(-2.0f, ov * r2, ov);
        Hw[e * U1S] = f2bf(h);
    }
}

__device__ __forceinline__ void fc_store(
    const short8& a2, const short8& a3, const short8 BF[2], float fcb,
    float s_reg[4], float* __restrict__ out, float* __restrict__ res,
    int rowbase, int ns, int t, int il, int quad)
{
    floatx4 so = {fcb, fcb, fcb, fcb};
    so = MFMA(a2, BF[0], so);
    so = MFMA(a3, BF[1], so);
    #pragma unroll
    for (int reg = 0; reg < 4; ++reg) {
        s_reg[reg] += so[reg] * DTC;
        if (quad < 2 && il < 8) {
            size_t o = ((size_t)(rowbase + 4 * quad + reg) * ns + t) * 8 + il;
            out[o] = s_reg[reg];
            res[o] = so[reg];
        }
    }
}

// 16 batch rows/block, 256 blocks (1/CU). Rows split into G (bb+0..7) and
// G' (bb+8..15), G' staggered HALF A STEP behind G. Each half-phase pairs one
// group's {ds_read + MFMA} with the other group's pure-trans cell update —
// independent data in ONE instruction stream, so read/MFMA latency hides
// under the partner's ~320-cycle trans burst (cross-block overlap proved
// unschedulable in R3: phase-locked blocks serialized on the VALU pipe).
// MFMA rows 8..15 are zero-padding; C-rows compacted onto 64 lanes for trans.
__global__ __launch_bounds__(256, 1) void lstm_mfma(
    const float* __restrict__ x,    const float* __restrict__ s0,
    const float* __restrict__ W_ih0,const float* __restrict__ W_hh0,
    const float* __restrict__ b_ih0,const float* __restrict__ b_hh0,
    const float* __restrict__ W_ih1,const float* __restrict__ W_hh1,
    const float* __restrict__ b_ih1,const float* __restrict__ b_hh1,
    const float* __restrict__ fc_W, const float* __restrict__ fc_b,
    const int* __restrict__ nsp,    float* __restrict__ out, int B)
{
    // U[g]: [16 rows][cols 0..63 = h_a bf16 | 64..127 = h_b bf16]; rows 8..15 stay 0.
    __shared__ __align__(16) unsigned short U[2][16 * U1S];

    const int ns   = nsp[0];
    const int tid  = threadIdx.x;
    const int lane = tid & 63;
    const int wave = tid >> 6;        // 0..3
    const int il   = lane & 15;
    const int quad = lane >> 4;
    const int bb   = blockIdx.x * 16;

    float* cal = out + (size_t)B * ns * 8;
    float* res = cal + ns;

    if (blockIdx.x == 0)
        for (int t = tid; t < ns; t += 256) cal[t] = t * DTC;

    for (int i = tid; i < 2 * 16 * U1S; i += 256) (&U[0][0])[i] = 0;

    // ---- weights (shared by both groups); gate pre-scale folded in ----
    short8 B0[4][2], B1[4][4], M2f[4][2], BF[2];
    floatx4 gsG[4], gsP[4];
    float gd[4], b1s[4];

    for (int j = 0; j < 4; ++j) {
        const float gam = (j == 2) ? LAM : -L2E;
        const int n = 64 * j + 16 * wave + il;
        float ws[8];
        #pragma unroll
        for (int p = 0; p < 8; ++p) ws[p] = W_ih0[n * 16 + 8 + p];

        #pragma unroll
        for (int kk = 0; kk < 2; ++kk) {
            short8 f;
            #pragma unroll
            for (int jj = 0; jj < 8; ++jj) {
                int k = 32 * kk + 8 * quad + jj;
                f[jj] = (short)f2bf(gam * W_hh0[n * 64 + k]);
            }
            B0[j][kk] = f;
        }
        #pragma unroll
        for (int kk = 0; kk < 4; ++kk) {
            short8 f;
            #pragma unroll
            for (int jj = 0; jj < 8; ++jj) {
                int k = 32 * kk + 8 * quad + jj;
                float w = (k < 64) ? W_ih1[n * 64 + k] : W_hh1[n * 64 + (k - 64)];
                f[jj] = (short)f2bf(gam * w);
            }
            B1[j][kk] = f;
        }
        #pragma unroll
        for (int kk = 0; kk < 2; ++kk) {        // M2 = W_s @ fc_W (s-path, exact)
            short8 f;
            #pragma unroll
            for (int jj = 0; jj < 8; ++jj) {
                int k = 32 * kk + 8 * quad + jj;
                float acc = 0.0f;
                #pragma unroll
                for (int p = 0; p < 8; ++p) acc += ws[p] * fc_W[p * 64 + k];
                f[jj] = (short)f2bf(gam * DTC * acc);
            }
            M2f[j][kk] = f;
        }
        float accb = 0.0f;
        #pragma unroll
        for (int p = 0; p < 8; ++p) accb += ws[p] * fc_b[p];
        gd[j] = gam * DTC * accb;

        float bcol = b_ih0[n] + b_hh0[n];
        floatx4 gvG, gvP;
        #pragma unroll
        for (int reg = 0; reg < 4; ++reg) {
            int m = (4 * quad + reg) & 7;       // clamp padding rows
            float aG = bcol, aP = bcol;
            #pragma unroll
            for (int k = 0; k < 8; ++k) {
                aG += x[(bb + m) * 8 + k] * W_ih0[n * 16 + k];
                aP += x[(bb + 8 + m) * 8 + k] * W_ih0[n * 16 + k];
            }
            #pragma unroll
            for (int p = 0; p < 8; ++p) {
                aG += ws[p] * s0[(bb + m) * 8 + p];
                aP += ws[p] * s0[(bb + 8 + m) * 8 + p];
            }
            gvG[reg] = gam * aG - gd[j];        // first update adds gd back
            gvP[reg] = gam * aP - gd[j];
        }
        gsG[j] = gvG;
        gsP[j] = gvP;
        b1s[j] = gam * (b_ih1[j * 64 + 16 * wave + il] * 0.0f + b_ih1[n] + b_hh1[n]);
    }
    #pragma unroll
    for (int kk = 0; kk < 2; ++kk) {            // FC head
        short8 f;
        #pragma unroll
        for (int jj = 0; jj < 8; ++jj) {
            int k = 32 * kk + 8 * quad + jj;
            float w = (il < 8) ? fc_W[il * 64 + k] : 0.0f;
            f[jj] = (short)f2bf(w);
        }
        BF[kk] = f;
    }
    const float fcb = (il < 8) ? fc_b[il] : 0.0f;

    // ---- state ----
    const int mbase = 4 * ((lane & 31) >> 4) + ((lane >> 5) << 1);  // compacted rows
    const int iidx  = 16 * wave + il;
    const int rowbase = bb + ((wave & 1) ? 8 : 0);   // wave0->G, wave1->G' FC rows
    float cAG[2] = {0, 0}, cBG[2] = {0, 0};
    float cAP[2] = {0, 0}, cBP[2] = {0, 0};
    float s_reg[4];
    #pragma unroll
    for (int reg = 0; reg < 4; ++reg) {
        int m = 4 * quad + reg;
        s_reg[reg] = (il < 8 && m < 8) ? s0[(rowbase + m) * 8 + il] : 0.0f;
    }

    short8 aG0 = {0,0,0,0,0,0,0,0}, aG1 = {0,0,0,0,0,0,0,0};
    short8 aG2, aG3, aP0, aP1, aP2, aP3;
    aP0 = aG0; aP1 = aG0;
    floatx4 q0G[4], p1G[4], q0P[4], p1P[4], q1G[4], q1P[4];

    const unsigned short* ArG = &U[0][il * U1S + 8 * quad];
    const unsigned short* ArP = &U[1][il * U1S + 8 * quad];
    unsigned short* HwG = &U[0][mbase * U1S + iidx];
    unsigned short* HwP = &U[1][mbase * U1S + iidx];

    wg_barrier();

    // ---- prologue: half-step stagger ----
    aG2 = *(const short8*)(ArG + 64);   // h_b(G,-1) = 0
    aG3 = *(const short8*)(ArG + 96);
    mfma_phase1(aG0, aG1, aG2, aG3, B0, B1, M2f, gsG, gd, b1s, q0G, p1G);
    wg_barrier();
    aP2 = *(const short8*)(ArP + 64);   // h_b(G',-1) = 0
    aP3 = *(const short8*)(ArP + 96);
    mfma_phase1(aP0, aP1, aP2, aP3, B0, B1, M2f, gsP, gd, b1s, q0P, p1P);
    cell_trans(q0G, cAG, HwG);          // h_a(G,0)
    wg_barrier();

    #pragma unroll 1
    for (int t = 0; t < ns; ++t) {
        // half A2: G q1-MFMA (+FC(G,t-1) on wave0)  ||  G' cell0-trans
        aG0 = *(const short8*)(ArG + 0);            // h_a(G,t)
        aG1 = *(const short8*)(ArG + 32);
        #pragma unroll
        for (int j = 0; j < 4; ++j)
            q1G[j] = MFMA(aG1, B1[j][1], MFMA(aG0, B1[j][0], p1G[j]));
        if (t && wave == 0)
            fc_store(aG2, aG3, BF, fcb, s_reg, out, res, rowbase, ns, t - 1, il, quad);
        cell_trans(q0P, cAP, HwP);                  // h_a(G',t)
        wg_barrier();

        // half B2: G cell1-trans  ||  G' q1-MFMA (+FC(G',t-1) on wave1)
        aP0 = *(const short8*)(ArP + 0);            // h_a(G',t)
        aP1 = *(const short8*)(ArP + 32);
        #pragma unroll
        for (int j = 0; j < 4; ++j)
            q1P[j] = MFMA(aP1, B1[j][1], MFMA(aP0, B1[j][0], p1P[j]));
        if (t && wave == 1)
            fc_store(aP2, aP3, BF, fcb, s_reg, out, res, rowbase, ns, t - 1, il, quad);
        cell_trans(q1G, cBG, HwG + 64);             // h_b(G,t)
        wg_barrier();

        // half A1(t+1): G phase1-MFMA  ||  G' cell1-trans
        aG2 = *(const short8*)(ArG + 64);           // h_b(G,t)
        aG3 = *(const short8*)(ArG + 96);
        mfma_phase1(aG0, aG1, aG2, aG3, B0, B1, M2f, gsG, gd, b1s, q0G, p1G);
        cell_trans(q1P, cBP, HwP + 64);             // h_b(G',t)
        wg_barrier();

        // half B1(t+1): G cell0-trans  ||  G' phase1-MFMA
        aP2 = *(const short8*)(ArP + 64);           // h_b(G',t)
        aP3 = *(const short8*)(ArP + 96);
        mfma_phase1(aP0, aP1, aP2, aP3, B0, B1, M2f, gsP, gd, b1s, q0P, p1P);
        cell_trans(q0G, cAG, HwG);                  // h_a(G,t+1) (t=ns-1: harmless)
        wg_barrier();
    }

    // epilogue: deferred FC for the final step of each group
    if (wave == 0)
        fc_store(aG2, aG3, BF, fcb, s_reg, out, res, rowbase, ns, ns - 1, il, quad);
    if (wave == 1)
        fc_store(aP2, aP3, BF, fcb, s_reg, out, res, rowbase, ns, ns - 1, il, quad);
}

extern "C" void kernel_launch(void* const* d_in, const int* in_sizes, int n_in,
                              void* d_out, int out_size, void* d_ws, size_t ws_size,
                              hipStream_t stream) {
    const float* x     = (const float*)d_in[0];
    const float* s0    = (const float*)d_in[1];
    const float* W_ih0 = (const float*)d_in[2];
    const float* W_hh0 = (const float*)d_in[3];
    const float* b_ih0 = (const float*)d_in[4];
    const float* b_hh0 = (const float*)d_in[5];
    const float* W_ih1 = (const float*)d_in[6];
    const float* W_hh1 = (const float*)d_in[7];
    const float* b_ih1 = (const float*)d_in[8];
    const float* b_hh1 = (const float*)d_in[9];
    const float* fc_W  = (const float*)d_in[10];
    const float* fc_b  = (const float*)d_in[11];
    const int*   nsp   = (const int*)d_in[12];
    (void)d_ws; (void)ws_size; (void)n_in; (void)out_size;
    int B = in_sizes[0] / 8;          // 4096
    dim3 grid(B / 16), block(256);    // 256 blocks -> 1 per CU
    hipLaunchKernelGGL(lstm_mfma, grid, block, 0, stream,
        x, s0, W_ih0, W_hh0, b_ih0, b_hh0, W_ih1, W_hh1, b_ih1, b_hh1,
        fc_W, fc_b, nsp, (float*)d_out, B);
}